// Round 12
// baseline (972.978 us; speedup 1.0000x reference)
//
#include <hip/hip_runtime.h>
#include <hip/hip_bf16.h>
#include <hip/hip_cooperative_groups.h>

namespace cg = cooperative_groups;

#define HDIM 128
#define CDIM 8
#define SCAN_CHUNK 4096

// Harness contract (pinned, R1-3): float32 -> const float*, edge_index -> const int*,
// output -> float*.
// R11 post-mortem: agg speed = resident waves x per-wave MLP; launch gaps ~35us.
// R12: ONE cooperative kernel (grid.sync between phases), 8 blocks/CU via
// __launch_bounds__(256,8) (VGPR<=64; R11 phases are 48-56) -> 32 waves/CU in
// agg phases. Fallback to R11 6-launch path if coop launch unavailable.

// ---------------- shared device helpers ----------------
__device__ __forceinline__ void bf8_fma(uint4 qv, float w, float* acc) {
    unsigned u[4] = {qv.x, qv.y, qv.z, qv.w};
#pragma unroll
    for (int i = 0; i < 4; i++) {
        float lo = __uint_as_float(u[i] << 16);
        float hi = __uint_as_float(u[i] & 0xFFFF0000u);
        acc[2 * i]     = fmaf(w, lo, acc[2 * i]);
        acc[2 * i + 1] = fmaf(w, hi, acc[2 * i + 1]);
    }
}

// 16 fs x 4 jg wave-per-node agg, depth-2 edge pipeline (VGPR-lean)
__device__ __forceinline__ void agg_core(const __hip_bfloat16* __restrict__ hin,
                                         const int* __restrict__ ptr,
                                         const int2* __restrict__ srcW,
                                         int node, int fs, int jg, float di,
                                         float acc[8]) {
#pragma unroll
    for (int k = 0; k < 8; k++) acc[k] = 0.f;
    if (jg == 0) {
        uint4 qv = ((const uint4*)(hin + (size_t)node * HDIM))[fs];
        bf8_fma(qv, di, acc);
    }
    int s = ptr[node], e = ptr[node + 1];
    int j0 = s + jg, j1 = s + jg + 4;
    int2 Z = make_int2(node, 0);
    int2 p0 = (j0 < e) ? srcW[j0] : Z;
    int2 p1 = (j1 < e) ? srcW[j1] : Z;
    int iters = (e - s + 7) >> 3;
    for (int t = 0; t < iters; t++) {
        int2 c0 = p0, c1 = p1;
        j0 += 8; j1 += 8;
        if (t + 1 < iters) {
            p0 = (j0 < e) ? srcW[j0] : Z;
            p1 = (j1 < e) ? srcW[j1] : Z;
        }
        uint4 q0 = ((const uint4*)(hin + (size_t)c0.x * HDIM))[fs];
        uint4 q1 = ((const uint4*)(hin + (size_t)c1.x * HDIM))[fs];
        bf8_fma(q0, __int_as_float(c0.y), acc);
        bf8_fma(q1, __int_as_float(c1.y), acc);
    }
#pragma unroll
    for (int k = 0; k < 8; k++) {
        acc[k] += __shfl_xor(acc[k], 16, 64);
        acc[k] += __shfl_xor(acc[k], 32, 64);
    }
}

// ---------------- THE MEGA KERNEL (cooperative) ----------------
__global__ __launch_bounds__(256, 8) void k_mega(
    const float* __restrict__ x, const int* __restrict__ ei,
    const float* __restrict__ W1, const float* __restrict__ b1,
    const float* __restrict__ W2, const float* __restrict__ b2,
    const float* __restrict__ Wfc, const float* __restrict__ bfc,
    float* __restrict__ out, __hip_bfloat16* __restrict__ bufH,
    __hip_bfloat16* __restrict__ bufH2, float* __restrict__ dinv,
    int* __restrict__ cnt, int* __restrict__ ptr, int* __restrict__ cursor,
    int2* __restrict__ srcW, int* __restrict__ bsum, int N, int E, int Gg) {
    cg::grid_group gg = cg::this_grid();
    __shared__ float xsh[32][HDIM];
    __shared__ int iw[4];
    int tid = threadIdx.x;
    int b = blockIdx.x, G = gridDim.x;
    int gtid = b * 256 + tid, gsz = G * 256;
    int lane = tid & 63, wid = tid >> 6;

    // P1: zero cnt
    for (int i = gtid; i < N; i += gsz) cnt[i] = 0;
    gg.sync();
    // P2: histogram over targets
    for (int e = gtid; e < E; e += gsz) atomicAdd(&cnt[ei[(size_t)E + e]], 1);
    gg.sync();
    // P3a: per-block chunk totals (chunk <= 196 for G >= 256)
    int chunk = (N + G - 1) / G;
    int idx = b * chunk + tid;
    int v = (tid < chunk && idx < N) ? cnt[idx] : 0;
    int t0 = v;
    for (int off = 32; off; off >>= 1) t0 += __shfl_down(t0, off, 64);
    if (lane == 0) iw[wid] = t0;
    __syncthreads();
    if (tid == 0) bsum[b] = iw[0] + iw[1] + iw[2] + iw[3];
    __syncthreads();
    gg.sync();
    // P3b: boff = prefix of bsum[0..b) (redundant per block, bsum L2-hot)
    int part = 0;
    for (int j = tid; j < b; j += 256) part += bsum[j];
    for (int off = 32; off; off >>= 1) part += __shfl_down(part, off, 64);
    if (lane == 0) iw[wid] = part;
    __syncthreads();
    int boff = iw[0] + iw[1] + iw[2] + iw[3];
    __syncthreads();
    // P3c: block-local exclusive scan -> ptr/cursor/dinv
    int xx = v;
    for (int off = 1; off < 64; off <<= 1) {
        int y = __shfl_up(xx, off, 64);
        if (lane >= off) xx += y;
    }
    if (lane == 63) iw[wid] = xx;
    __syncthreads();
    int woff = 0;
    for (int w2 = 0; w2 < wid; w2++) woff += iw[w2];
    int excl = boff + woff + xx - v;
    if (tid < chunk && idx < N) {
        ptr[idx] = excl;
        cursor[idx] = excl;
        dinv[idx] = rsqrtf((float)v + 1.0f);   // +1 self-loop
    }
    if (b == 0 && tid == 0) ptr[N] = E;
    gg.sync();

    // P4: stripe-interleaved [scatter | gemm1]; units u: u%3<2 scatter, ==2 gemm
    int units = 3 * Gg;
    for (int u = b; u < units; u += G) {
        int q = u / 3, k3 = u % 3;
        if (k3 < 2) {
            int e = (2 * q + k3) * 256 + tid;
            if (e < E) {
                int c = ei[(size_t)E + e];
                int r = ei[e];
                int pos = atomicAdd(&cursor[c], 1);
                srcW[pos] = make_int2(r, __float_as_int(dinv[r]));
            }
        } else {
            int r0 = q * 32;
            __syncthreads();   // protect xsh from previous gemm unit
            for (int id2 = tid; id2 < 32 * HDIM / 4; id2 += 256) {
                int row = id2 >> 5;
                int kk = (id2 & 31) * 4;
                int gr = r0 + row;
                float4 vv = make_float4(0.f, 0.f, 0.f, 0.f);
                if (gr < N) vv = *(const float4*)(x + (size_t)gr * HDIM + kk);
                *(float4*)&xsh[row][kk] = vv;
            }
            __syncthreads();
            int c = tid & 127, g = tid >> 7;
            float acc[16];
#pragma unroll
            for (int r = 0; r < 16; r++) acc[r] = 0.f;
            for (int k4 = 0; k4 < HDIM / 4; k4++) {
                int k = k4 * 4;
                float w0 = W1[(size_t)(k + 0) * HDIM + c];
                float w1 = W1[(size_t)(k + 1) * HDIM + c];
                float w2 = W1[(size_t)(k + 2) * HDIM + c];
                float w3 = W1[(size_t)(k + 3) * HDIM + c];
#pragma unroll
                for (int r = 0; r < 16; r++) {
                    float4 xv = *(const float4*)&xsh[g * 16 + r][k];
                    acc[r] = fmaf(xv.x, w0, fmaf(xv.y, w1, fmaf(xv.z, w2, fmaf(xv.w, w3, acc[r]))));
                }
            }
#pragma unroll
            for (int r = 0; r < 16; r++) {
                int gr = r0 + g * 16 + r;
                if (gr < N) bufH[(size_t)gr * HDIM + c] = __float2bfloat16(acc[r]);
            }
        }
    }
    gg.sync();

    // P5: agg1 (bufH) -> LDS -> gemm2(W2) -> bufH2, 32-node tiles
    int fs = lane & 15, jg = lane >> 4;
    for (int tile = b; tile < Gg; tile += G) {
        int base = tile * 32;
        __syncthreads();   // protect xsh reuse
        for (int i2 = 0; i2 < 8; i2++) {
            int lr = wid * 8 + i2;
            int node = base + lr;
            if (node < N) {
                float di = dinv[node];
                float acc[8];
                agg_core(bufH, ptr, srcW, node, fs, jg, di, acc);
                if (jg == 0) {
                    const float4* b4 = (const float4*)(b1 + fs * 8);
                    float4 bb0 = b4[0], bb1 = b4[1];
                    float4 v0 = make_float4(fmaf(di, acc[0], bb0.x), fmaf(di, acc[1], bb0.y),
                                            fmaf(di, acc[2], bb0.z), fmaf(di, acc[3], bb0.w));
                    float4 v1 = make_float4(fmaf(di, acc[4], bb1.x), fmaf(di, acc[5], bb1.y),
                                            fmaf(di, acc[6], bb1.z), fmaf(di, acc[7], bb1.w));
                    *(float4*)&xsh[lr][fs * 8]     = v0;
                    *(float4*)&xsh[lr][fs * 8 + 4] = v1;
                }
            } else if (jg == 0) {
                float4 z = make_float4(0.f, 0.f, 0.f, 0.f);
                *(float4*)&xsh[lr][fs * 8]     = z;
                *(float4*)&xsh[lr][fs * 8 + 4] = z;
            }
        }
        __syncthreads();
        int c = tid & 127, g = tid >> 7;
        float acc[16];
#pragma unroll
        for (int r = 0; r < 16; r++) acc[r] = 0.f;
        for (int k4 = 0; k4 < HDIM / 4; k4++) {
            int k = k4 * 4;
            float w0 = W2[(size_t)(k + 0) * HDIM + c];
            float w1 = W2[(size_t)(k + 1) * HDIM + c];
            float w2 = W2[(size_t)(k + 2) * HDIM + c];
            float w3 = W2[(size_t)(k + 3) * HDIM + c];
#pragma unroll
            for (int r = 0; r < 16; r++) {
                float4 xv = *(const float4*)&xsh[g * 16 + r][k];
                acc[r] = fmaf(xv.x, w0, fmaf(xv.y, w1, fmaf(xv.z, w2, fmaf(xv.w, w3, acc[r]))));
            }
        }
#pragma unroll
        for (int r = 0; r < 16; r++) {
            int gr = base + g * 16 + r;
            if (gr < N) bufH2[(size_t)gr * HDIM + c] = __float2bfloat16(acc[r]);
        }
    }
    gg.sync();

    // P6: agg2 (bufH2) + fused FC -> out
    int quads = (N + 3) / 4;
    for (int qd = b; qd < quads; qd += G) {
        int node = qd * 4 + wid;
        if (node >= N) continue;
        float di = dinv[node];
        float acc[8];
        agg_core(bufH2, ptr, srcW, node, fs, jg, di, acc);
        const float4* b4 = (const float4*)(b2 + fs * 8);
        float4 bb0 = b4[0], bb1 = b4[1];
        float h[8];
        h[0] = fmaf(di, acc[0], bb0.x); h[1] = fmaf(di, acc[1], bb0.y);
        h[2] = fmaf(di, acc[2], bb0.z); h[3] = fmaf(di, acc[3], bb0.w);
        h[4] = fmaf(di, acc[4], bb1.x); h[5] = fmaf(di, acc[5], bb1.y);
        h[6] = fmaf(di, acc[6], bb1.z); h[7] = fmaf(di, acc[7], bb1.w);
        int c0 = jg * 2;
        float p0 = 0.f, p1 = 0.f;
#pragma unroll
        for (int k = 0; k < 8; k++) {
            const float* wr = Wfc + (size_t)(fs * 8 + k) * CDIM + c0;
            p0 = fmaf(h[k], wr[0], p0);
            p1 = fmaf(h[k], wr[1], p1);
        }
#pragma unroll
        for (int off = 1; off < 16; off <<= 1) {
            p0 += __shfl_xor(p0, off, 64);
            p1 += __shfl_xor(p1, off, 64);
        }
        if (fs == 0) {
            out[(size_t)node * CDIM + c0]     = p0 + bfc[c0];
            out[(size_t)node * CDIM + c0 + 1] = p1 + bfc[c0 + 1];
        }
    }
}

// ================= FALLBACK PATH: R11 kernels (proven) =================
__global__ void k_hist(const int* __restrict__ col, int* __restrict__ cnt, int E) {
    int e = blockIdx.x * blockDim.x + threadIdx.x;
    if (e < E) atomicAdd(&cnt[col[e]], 1);
}

__global__ __launch_bounds__(256) void k_scan(const int* __restrict__ cnt,
                                              int* __restrict__ status,
                                              int* __restrict__ ptr,
                                              int* __restrict__ cursor,
                                              float* __restrict__ dinv,
                                              int n, int Etot) {
    int b = blockIdx.x, tid = threadIdx.x;
    int base = b * SCAN_CHUNK + tid * 16;
    int v[16];
    int s = 0;
#pragma unroll
    for (int j = 0; j < 16; j++) {
        int i = base + j;
        v[j] = (i < n) ? cnt[i] : 0;
        s += v[j];
    }
    int lane = tid & 63, wid = tid >> 6;
    int x = s;
    for (int off = 1; off < 64; off <<= 1) {
        int y = __shfl_up(x, off, 64);
        if (lane >= off) x += y;
    }
    __shared__ int wtot[4];
    __shared__ int sprefix;
    if (lane == 63) wtot[wid] = x;
    __syncthreads();
    if (tid == 0) {
        int tot = wtot[0] + wtot[1] + wtot[2] + wtot[3];
        atomicExch(&status[b], tot + 1);
        int pre = 0;
        for (int p = 0; p < b; p++) {
            int vv;
            do { vv = atomicAdd(&status[p], 0); } while (vv == 0);
            pre += vv - 1;
        }
        sprefix = pre;
        if (b == 0) ptr[n] = Etot;
    }
    __syncthreads();
    int woff = 0;
    for (int w = 0; w < wid; w++) woff += wtot[w];
    int excl = sprefix + woff + (x - s);
#pragma unroll
    for (int j = 0; j < 16; j++) {
        int i = base + j;
        if (i < n) {
            ptr[i] = excl;
            cursor[i] = excl;
            dinv[i] = rsqrtf((float)v[j] + 1.0f);
        }
        excl += v[j];
    }
}

__global__ __launch_bounds__(256) void k_scatter_gemm(const int* __restrict__ ei,
                                                      int* __restrict__ cursor,
                                                      int2* __restrict__ srcW, int E,
                                                      const float* __restrict__ dinv,
                                                      const float* __restrict__ X,
                                                      const float* __restrict__ W,
                                                      __hip_bfloat16* __restrict__ Y,
                                                      int nrows) {
    int tid = threadIdx.x;
    int q = blockIdx.x / 3, k3 = blockIdx.x % 3;
    if (k3 < 2) {
        int e = (2 * q + k3) * 256 + tid;
        if (e < E) {
            int c = ei[(size_t)E + e];
            int r = ei[e];
            int pos = atomicAdd(&cursor[c], 1);
            srcW[pos] = make_int2(r, __float_as_int(dinv[r]));
        }
    } else {
        __shared__ float xsh[32][HDIM];
        int c = tid & 127;
        int g = tid >> 7;
        int r0 = q * 32;
        for (int idx = tid; idx < 32 * HDIM / 4; idx += 256) {
            int row = idx >> 5;
            int kk = (idx & 31) * 4;
            int gr = r0 + row;
            float4 v = make_float4(0.f, 0.f, 0.f, 0.f);
            if (gr < nrows) v = *(const float4*)(X + (size_t)gr * HDIM + kk);
            *(float4*)&xsh[row][kk] = v;
        }
        __syncthreads();
        float acc[16];
#pragma unroll
        for (int r = 0; r < 16; r++) acc[r] = 0.f;
        for (int k4 = 0; k4 < HDIM / 4; k4++) {
            int k = k4 * 4;
            float w0 = W[(size_t)(k + 0) * HDIM + c];
            float w1 = W[(size_t)(k + 1) * HDIM + c];
            float w2 = W[(size_t)(k + 2) * HDIM + c];
            float w3 = W[(size_t)(k + 3) * HDIM + c];
#pragma unroll
            for (int r = 0; r < 16; r++) {
                float4 xv = *(const float4*)&xsh[g * 16 + r][k];
                acc[r] = fmaf(xv.x, w0, fmaf(xv.y, w1, fmaf(xv.z, w2, fmaf(xv.w, w3, acc[r]))));
            }
        }
#pragma unroll
        for (int r = 0; r < 16; r++) {
            int gr = r0 + g * 16 + r;
            if (gr < nrows) Y[(size_t)gr * HDIM + c] = __float2bfloat16(acc[r]);
        }
    }
}

__global__ __launch_bounds__(256) void k_agg_gemm(const __hip_bfloat16* __restrict__ hin,
                                                  __hip_bfloat16* __restrict__ hout,
                                                  const int* __restrict__ ptr,
                                                  const int2* __restrict__ srcW,
                                                  const float* __restrict__ dinv,
                                                  const float* __restrict__ bias,
                                                  const float* __restrict__ W2, int n) {
    __shared__ float xsh[32][HDIM];
    int tid = threadIdx.x;
    int w = tid >> 6, lane = tid & 63;
    int fs = lane & 15, jg = lane >> 4;
    int base = blockIdx.x * 32;
    for (int i = 0; i < 8; i++) {
        int lr = w * 8 + i;
        int node = base + lr;
        if (node < n) {
            float di = dinv[node];
            float acc[8];
            agg_core(hin, ptr, srcW, node, fs, jg, di, acc);
            if (jg == 0) {
                const float4* b4 = (const float4*)(bias + fs * 8);
                float4 bb0 = b4[0], bb1 = b4[1];
                float4 v0 = make_float4(fmaf(di, acc[0], bb0.x), fmaf(di, acc[1], bb0.y),
                                        fmaf(di, acc[2], bb0.z), fmaf(di, acc[3], bb0.w));
                float4 v1 = make_float4(fmaf(di, acc[4], bb1.x), fmaf(di, acc[5], bb1.y),
                                        fmaf(di, acc[6], bb1.z), fmaf(di, acc[7], bb1.w));
                *(float4*)&xsh[lr][fs * 8]     = v0;
                *(float4*)&xsh[lr][fs * 8 + 4] = v1;
            }
        } else if (jg == 0) {
            float4 z = make_float4(0.f, 0.f, 0.f, 0.f);
            *(float4*)&xsh[lr][fs * 8]     = z;
            *(float4*)&xsh[lr][fs * 8 + 4] = z;
        }
    }
    __syncthreads();
    int c = tid & 127, g = tid >> 7;
    float acc[16];
#pragma unroll
    for (int r = 0; r < 16; r++) acc[r] = 0.f;
    for (int k4 = 0; k4 < HDIM / 4; k4++) {
        int k = k4 * 4;
        float w0 = W2[(size_t)(k + 0) * HDIM + c];
        float w1 = W2[(size_t)(k + 1) * HDIM + c];
        float w2 = W2[(size_t)(k + 2) * HDIM + c];
        float w3 = W2[(size_t)(k + 3) * HDIM + c];
#pragma unroll
        for (int r = 0; r < 16; r++) {
            float4 xv = *(const float4*)&xsh[g * 16 + r][k];
            acc[r] = fmaf(xv.x, w0, fmaf(xv.y, w1, fmaf(xv.z, w2, fmaf(xv.w, w3, acc[r]))));
        }
    }
#pragma unroll
    for (int r = 0; r < 16; r++) {
        int gr = base + g * 16 + r;
        if (gr < n) hout[(size_t)gr * HDIM + c] = __float2bfloat16(acc[r]);
    }
}

__global__ __launch_bounds__(256) void k_agg_fc(const __hip_bfloat16* __restrict__ hin,
                                                const int* __restrict__ ptr,
                                                const int2* __restrict__ srcW,
                                                const float* __restrict__ dinv,
                                                const float* __restrict__ bias,
                                                const float* __restrict__ Wfc,
                                                const float* __restrict__ bfc,
                                                float* __restrict__ out, int n) {
    int node = blockIdx.x * 4 + (threadIdx.x >> 6);
    if (node >= n) return;
    int lane = threadIdx.x & 63;
    int fs = lane & 15, jg = lane >> 4;
    float di = dinv[node];
    float acc[8];
    agg_core(hin, ptr, srcW, node, fs, jg, di, acc);
    const float4* b4 = (const float4*)(bias + fs * 8);
    float4 bb0 = b4[0], bb1 = b4[1];
    float h[8];
    h[0] = fmaf(di, acc[0], bb0.x); h[1] = fmaf(di, acc[1], bb0.y);
    h[2] = fmaf(di, acc[2], bb0.z); h[3] = fmaf(di, acc[3], bb0.w);
    h[4] = fmaf(di, acc[4], bb1.x); h[5] = fmaf(di, acc[5], bb1.y);
    h[6] = fmaf(di, acc[6], bb1.z); h[7] = fmaf(di, acc[7], bb1.w);
    int c0 = jg * 2;
    float p0 = 0.f, p1 = 0.f;
#pragma unroll
    for (int k = 0; k < 8; k++) {
        const float* wr = Wfc + (size_t)(fs * 8 + k) * CDIM + c0;
        p0 = fmaf(h[k], wr[0], p0);
        p1 = fmaf(h[k], wr[1], p1);
    }
#pragma unroll
    for (int off = 1; off < 16; off <<= 1) {
        p0 += __shfl_xor(p0, off, 64);
        p1 += __shfl_xor(p1, off, 64);
    }
    if (fs == 0) {
        out[(size_t)node * CDIM + c0]     = p0 + bfc[c0];
        out[(size_t)node * CDIM + c0 + 1] = p1 + bfc[c0 + 1];
    }
}

extern "C" void kernel_launch(void* const* d_in, const int* in_sizes, int n_in,
                              void* d_out, int out_size, void* d_ws, size_t ws_size,
                              hipStream_t stream) {
    const float* x   = (const float*)d_in[0];
    const int*   ei  = (const int*)d_in[1];
    const float* W1  = (const float*)d_in[2];
    const float* b1  = (const float*)d_in[3];
    const float* W2  = (const float*)d_in[4];
    const float* b2  = (const float*)d_in[5];
    const float* Wfc = (const float*)d_in[6];
    const float* bfc = (const float*)d_in[7];
    float* out = (float*)d_out;

    int N = in_sizes[0] / HDIM;   // 50000
    int E = in_sizes[1] / 2;      // 800000
    int Gg = (N + 31) / 32;       // 1563

    // workspace layout
    __hip_bfloat16* bufH  = (__hip_bfloat16*)d_ws;                       // N*128 bf16
    __hip_bfloat16* bufH2 = bufH + (size_t)N * HDIM;                     // N*128 bf16
    float* dinv   = (float*)(bufH2 + (size_t)N * HDIM);  // N
    int*   cnt    = (int*)(dinv + N);                    // N
    int*   status = cnt + N;                             // 16  (fallback scan)
    int*   ptr    = status + 16;                         // N+1
    int*   cursor = ptr + (N + 1);                       // N
    int*   bsum   = cursor + N;                          // 2048
    int2*  srcW   = (int2*)(((uintptr_t)(bsum + 2048) + 15) & ~(uintptr_t)15);  // E int2

    // ---- primary: single cooperative launch ----
    int occ = 0;
    hipError_t oe = hipOccupancyMaxActiveBlocksPerMultiprocessor(
        &occ, reinterpret_cast<const void*>(k_mega), 256, 0);
    bool coop = (oe == hipSuccess && occ >= 1);
    if (coop) {
        int bpc = occ > 8 ? 8 : occ;
        int grid = bpc * 256;   // 256 CUs on MI355X
        void* args[] = {(void*)&x,    (void*)&ei,   (void*)&W1,   (void*)&b1,
                        (void*)&W2,   (void*)&b2,   (void*)&Wfc,  (void*)&bfc,
                        (void*)&out,  (void*)&bufH, (void*)&bufH2,(void*)&dinv,
                        (void*)&cnt,  (void*)&ptr,  (void*)&cursor,(void*)&srcW,
                        (void*)&bsum, (void*)&N,    (void*)&E,    (void*)&Gg};
        hipError_t le = hipLaunchCooperativeKernel(
            reinterpret_cast<const void*>(k_mega), dim3(grid), dim3(256),
            args, 0, stream);
        coop = (le == hipSuccess);
    }
    if (!coop) {
        // ---- fallback: proven R11 6-launch path ----
        const int B = (N + SCAN_CHUNK - 1) / SCAN_CHUNK;
        hipMemsetAsync(cnt, 0, (size_t)(N + 16) * sizeof(int), stream);
        k_hist<<<(E + 255) / 256, 256, 0, stream>>>(ei + E, cnt, E);
        k_scan<<<B, 256, 0, stream>>>(cnt, status, ptr, cursor, dinv, N, E);
        k_scatter_gemm<<<3 * Gg, 256, 0, stream>>>(ei, cursor, srcW, E, dinv, x, W1, bufH, N);
        k_agg_gemm<<<Gg, 256, 0, stream>>>(bufH, bufH2, ptr, srcW, dinv, b1, W2, N);
        k_agg_fc<<<(N + 3) / 4, 256, 0, stream>>>(bufH2, ptr, srcW, dinv, b2, Wfc, bfc, out, N);
    }
}

// Round 13
// 729.754 us; speedup vs baseline: 1.3333x; 1.3333x over previous
//
#include <hip/hip_runtime.h>
#include <hip/hip_bf16.h>
#include <hip/hip_cooperative_groups.h>

namespace cg = cooperative_groups;

#define HDIM 128
#define CDIM 8
#define SCAN_CHUNK 4096

// Harness contract (pinned, R1-3): float32 -> const float*, edge_index -> const int*,
// output -> float*.
// R12 post-mortem: __launch_bounds__(256,8) capped VGPR at 32 -> agg/gemm spilled
// to scratch (WRITE 12.5->106MB, VALUBusy 6%, 973us). Fix: (256,4) -> cap 128,
// natural alloc ~56-64, no spills; grid sized by occupancy query (8 blocks/CU
// if <=64 VGPR). R11 6-launch fallback retained.

// ---------------- shared device helpers ----------------
__device__ __forceinline__ void bf8_fma(uint4 qv, float w, float* acc) {
    unsigned u[4] = {qv.x, qv.y, qv.z, qv.w};
#pragma unroll
    for (int i = 0; i < 4; i++) {
        float lo = __uint_as_float(u[i] << 16);
        float hi = __uint_as_float(u[i] & 0xFFFF0000u);
        acc[2 * i]     = fmaf(w, lo, acc[2 * i]);
        acc[2 * i + 1] = fmaf(w, hi, acc[2 * i + 1]);
    }
}

// 16 fs x 4 jg wave-per-node agg, depth-2 edge pipeline (VGPR-lean)
__device__ __forceinline__ void agg_core(const __hip_bfloat16* __restrict__ hin,
                                         const int* __restrict__ ptr,
                                         const int2* __restrict__ srcW,
                                         int node, int fs, int jg, float di,
                                         float acc[8]) {
#pragma unroll
    for (int k = 0; k < 8; k++) acc[k] = 0.f;
    if (jg == 0) {
        uint4 qv = ((const uint4*)(hin + (size_t)node * HDIM))[fs];
        bf8_fma(qv, di, acc);
    }
    int s = ptr[node], e = ptr[node + 1];
    int j0 = s + jg, j1 = s + jg + 4;
    int2 Z = make_int2(node, 0);
    int2 p0 = (j0 < e) ? srcW[j0] : Z;
    int2 p1 = (j1 < e) ? srcW[j1] : Z;
    int iters = (e - s + 7) >> 3;
    for (int t = 0; t < iters; t++) {
        int2 c0 = p0, c1 = p1;
        j0 += 8; j1 += 8;
        if (t + 1 < iters) {
            p0 = (j0 < e) ? srcW[j0] : Z;
            p1 = (j1 < e) ? srcW[j1] : Z;
        }
        uint4 q0 = ((const uint4*)(hin + (size_t)c0.x * HDIM))[fs];
        uint4 q1 = ((const uint4*)(hin + (size_t)c1.x * HDIM))[fs];
        bf8_fma(q0, __int_as_float(c0.y), acc);
        bf8_fma(q1, __int_as_float(c1.y), acc);
    }
#pragma unroll
    for (int k = 0; k < 8; k++) {
        acc[k] += __shfl_xor(acc[k], 16, 64);
        acc[k] += __shfl_xor(acc[k], 32, 64);
    }
}

// ---------------- THE MEGA KERNEL (cooperative) ----------------
// min-waves/EU = 4 -> VGPR cap 128 (natural ~56-64, NO spills; R12's =8 capped
// at 32 and spilled everything).
__global__ __launch_bounds__(256, 4) void k_mega(
    const float* __restrict__ x, const int* __restrict__ ei,
    const float* __restrict__ W1, const float* __restrict__ b1,
    const float* __restrict__ W2, const float* __restrict__ b2,
    const float* __restrict__ Wfc, const float* __restrict__ bfc,
    float* __restrict__ out, __hip_bfloat16* __restrict__ bufH,
    __hip_bfloat16* __restrict__ bufH2, float* __restrict__ dinv,
    int* __restrict__ cnt, int* __restrict__ ptr, int* __restrict__ cursor,
    int2* __restrict__ srcW, int* __restrict__ bsum, int N, int E, int Gg) {
    cg::grid_group gg = cg::this_grid();
    __shared__ float xsh[32][HDIM];
    __shared__ int iw[4];
    int tid = threadIdx.x;
    int b = blockIdx.x, G = gridDim.x;
    int gtid = b * 256 + tid, gsz = G * 256;
    int lane = tid & 63, wid = tid >> 6;

    // P1: zero cnt
    for (int i = gtid; i < N; i += gsz) cnt[i] = 0;
    gg.sync();
    // P2: histogram over targets
    for (int e = gtid; e < E; e += gsz) atomicAdd(&cnt[ei[(size_t)E + e]], 1);
    gg.sync();
    // P3a: per-block chunk totals
    int chunk = (N + G - 1) / G;
    int idx = b * chunk + tid;
    int v = (tid < chunk && idx < N) ? cnt[idx] : 0;
    int t0 = v;
    for (int off = 32; off; off >>= 1) t0 += __shfl_down(t0, off, 64);
    if (lane == 0) iw[wid] = t0;
    __syncthreads();
    if (tid == 0) bsum[b] = iw[0] + iw[1] + iw[2] + iw[3];
    __syncthreads();
    gg.sync();
    // P3b: boff = prefix of bsum[0..b)
    int part = 0;
    for (int j = tid; j < b; j += 256) part += bsum[j];
    for (int off = 32; off; off >>= 1) part += __shfl_down(part, off, 64);
    if (lane == 0) iw[wid] = part;
    __syncthreads();
    int boff = iw[0] + iw[1] + iw[2] + iw[3];
    __syncthreads();
    // P3c: block-local exclusive scan -> ptr/cursor/dinv
    int xx = v;
    for (int off = 1; off < 64; off <<= 1) {
        int y = __shfl_up(xx, off, 64);
        if (lane >= off) xx += y;
    }
    if (lane == 63) iw[wid] = xx;
    __syncthreads();
    int woff = 0;
    for (int w2 = 0; w2 < wid; w2++) woff += iw[w2];
    int excl = boff + woff + xx - v;
    if (tid < chunk && idx < N) {
        ptr[idx] = excl;
        cursor[idx] = excl;
        dinv[idx] = rsqrtf((float)v + 1.0f);   // +1 self-loop
    }
    if (b == 0 && tid == 0) ptr[N] = E;
    gg.sync();

    // P4: stripe-interleaved [scatter | gemm1]
    int units = 3 * Gg;
    for (int u = b; u < units; u += G) {
        int q = u / 3, k3 = u % 3;
        if (k3 < 2) {
            int e = (2 * q + k3) * 256 + tid;
            if (e < E) {
                int c = ei[(size_t)E + e];
                int r = ei[e];
                int pos = atomicAdd(&cursor[c], 1);
                srcW[pos] = make_int2(r, __float_as_int(dinv[r]));
            }
        } else {
            int r0 = q * 32;
            __syncthreads();
            for (int id2 = tid; id2 < 32 * HDIM / 4; id2 += 256) {
                int row = id2 >> 5;
                int kk = (id2 & 31) * 4;
                int gr = r0 + row;
                float4 vv = make_float4(0.f, 0.f, 0.f, 0.f);
                if (gr < N) vv = *(const float4*)(x + (size_t)gr * HDIM + kk);
                *(float4*)&xsh[row][kk] = vv;
            }
            __syncthreads();
            int c = tid & 127, g = tid >> 7;
            float acc[16];
#pragma unroll
            for (int r = 0; r < 16; r++) acc[r] = 0.f;
            for (int k4 = 0; k4 < HDIM / 4; k4++) {
                int k = k4 * 4;
                float w0 = W1[(size_t)(k + 0) * HDIM + c];
                float w1 = W1[(size_t)(k + 1) * HDIM + c];
                float w2 = W1[(size_t)(k + 2) * HDIM + c];
                float w3 = W1[(size_t)(k + 3) * HDIM + c];
#pragma unroll
                for (int r = 0; r < 16; r++) {
                    float4 xv = *(const float4*)&xsh[g * 16 + r][k];
                    acc[r] = fmaf(xv.x, w0, fmaf(xv.y, w1, fmaf(xv.z, w2, fmaf(xv.w, w3, acc[r]))));
                }
            }
#pragma unroll
            for (int r = 0; r < 16; r++) {
                int gr = r0 + g * 16 + r;
                if (gr < N) bufH[(size_t)gr * HDIM + c] = __float2bfloat16(acc[r]);
            }
        }
    }
    gg.sync();

    // P5: agg1 (bufH) -> LDS -> gemm2(W2) -> bufH2, 32-node tiles
    int fs = lane & 15, jg = lane >> 4;
    for (int tile = b; tile < Gg; tile += G) {
        int base = tile * 32;
        __syncthreads();
        for (int i2 = 0; i2 < 8; i2++) {
            int lr = wid * 8 + i2;
            int node = base + lr;
            if (node < N) {
                float di = dinv[node];
                float acc[8];
                agg_core(bufH, ptr, srcW, node, fs, jg, di, acc);
                if (jg == 0) {
                    const float4* b4 = (const float4*)(b1 + fs * 8);
                    float4 bb0 = b4[0], bb1 = b4[1];
                    float4 v0 = make_float4(fmaf(di, acc[0], bb0.x), fmaf(di, acc[1], bb0.y),
                                            fmaf(di, acc[2], bb0.z), fmaf(di, acc[3], bb0.w));
                    float4 v1 = make_float4(fmaf(di, acc[4], bb1.x), fmaf(di, acc[5], bb1.y),
                                            fmaf(di, acc[6], bb1.z), fmaf(di, acc[7], bb1.w));
                    *(float4*)&xsh[lr][fs * 8]     = v0;
                    *(float4*)&xsh[lr][fs * 8 + 4] = v1;
                }
            } else if (jg == 0) {
                float4 z = make_float4(0.f, 0.f, 0.f, 0.f);
                *(float4*)&xsh[lr][fs * 8]     = z;
                *(float4*)&xsh[lr][fs * 8 + 4] = z;
            }
        }
        __syncthreads();
        int c = tid & 127, g = tid >> 7;
        float acc[16];
#pragma unroll
        for (int r = 0; r < 16; r++) acc[r] = 0.f;
        for (int k4 = 0; k4 < HDIM / 4; k4++) {
            int k = k4 * 4;
            float w0 = W2[(size_t)(k + 0) * HDIM + c];
            float w1 = W2[(size_t)(k + 1) * HDIM + c];
            float w2 = W2[(size_t)(k + 2) * HDIM + c];
            float w3 = W2[(size_t)(k + 3) * HDIM + c];
#pragma unroll
            for (int r = 0; r < 16; r++) {
                float4 xv = *(const float4*)&xsh[g * 16 + r][k];
                acc[r] = fmaf(xv.x, w0, fmaf(xv.y, w1, fmaf(xv.z, w2, fmaf(xv.w, w3, acc[r]))));
            }
        }
#pragma unroll
        for (int r = 0; r < 16; r++) {
            int gr = base + g * 16 + r;
            if (gr < N) bufH2[(size_t)gr * HDIM + c] = __float2bfloat16(acc[r]);
        }
    }
    gg.sync();

    // P6: agg2 (bufH2) + fused FC -> out
    int quads = (N + 3) / 4;
    for (int qd = b; qd < quads; qd += G) {
        int node = qd * 4 + wid;
        if (node >= N) continue;
        float di = dinv[node];
        float acc[8];
        agg_core(bufH2, ptr, srcW, node, fs, jg, di, acc);
        const float4* b4 = (const float4*)(b2 + fs * 8);
        float4 bb0 = b4[0], bb1 = b4[1];
        float h[8];
        h[0] = fmaf(di, acc[0], bb0.x); h[1] = fmaf(di, acc[1], bb0.y);
        h[2] = fmaf(di, acc[2], bb0.z); h[3] = fmaf(di, acc[3], bb0.w);
        h[4] = fmaf(di, acc[4], bb1.x); h[5] = fmaf(di, acc[5], bb1.y);
        h[6] = fmaf(di, acc[6], bb1.z); h[7] = fmaf(di, acc[7], bb1.w);
        int c0 = jg * 2;
        float p0 = 0.f, p1 = 0.f;
#pragma unroll
        for (int k = 0; k < 8; k++) {
            const float* wr = Wfc + (size_t)(fs * 8 + k) * CDIM + c0;
            p0 = fmaf(h[k], wr[0], p0);
            p1 = fmaf(h[k], wr[1], p1);
        }
#pragma unroll
        for (int off = 1; off < 16; off <<= 1) {
            p0 += __shfl_xor(p0, off, 64);
            p1 += __shfl_xor(p1, off, 64);
        }
        if (fs == 0) {
            out[(size_t)node * CDIM + c0]     = p0 + bfc[c0];
            out[(size_t)node * CDIM + c0 + 1] = p1 + bfc[c0 + 1];
        }
    }
}

// ================= FALLBACK PATH: R11 kernels (proven, 327.8us) =================
__global__ void k_hist(const int* __restrict__ col, int* __restrict__ cnt, int E) {
    int e = blockIdx.x * blockDim.x + threadIdx.x;
    if (e < E) atomicAdd(&cnt[col[e]], 1);
}

__global__ __launch_bounds__(256) void k_scan(const int* __restrict__ cnt,
                                              int* __restrict__ status,
                                              int* __restrict__ ptr,
                                              int* __restrict__ cursor,
                                              float* __restrict__ dinv,
                                              int n, int Etot) {
    int b = blockIdx.x, tid = threadIdx.x;
    int base = b * SCAN_CHUNK + tid * 16;
    int v[16];
    int s = 0;
#pragma unroll
    for (int j = 0; j < 16; j++) {
        int i = base + j;
        v[j] = (i < n) ? cnt[i] : 0;
        s += v[j];
    }
    int lane = tid & 63, wid = tid >> 6;
    int x = s;
    for (int off = 1; off < 64; off <<= 1) {
        int y = __shfl_up(x, off, 64);
        if (lane >= off) x += y;
    }
    __shared__ int wtot[4];
    __shared__ int sprefix;
    if (lane == 63) wtot[wid] = x;
    __syncthreads();
    if (tid == 0) {
        int tot = wtot[0] + wtot[1] + wtot[2] + wtot[3];
        atomicExch(&status[b], tot + 1);
        int pre = 0;
        for (int p = 0; p < b; p++) {
            int vv;
            do { vv = atomicAdd(&status[p], 0); } while (vv == 0);
            pre += vv - 1;
        }
        sprefix = pre;
        if (b == 0) ptr[n] = Etot;
    }
    __syncthreads();
    int woff = 0;
    for (int w = 0; w < wid; w++) woff += wtot[w];
    int excl = sprefix + woff + (x - s);
#pragma unroll
    for (int j = 0; j < 16; j++) {
        int i = base + j;
        if (i < n) {
            ptr[i] = excl;
            cursor[i] = excl;
            dinv[i] = rsqrtf((float)v[j] + 1.0f);
        }
        excl += v[j];
    }
}

__global__ __launch_bounds__(256) void k_scatter_gemm(const int* __restrict__ ei,
                                                      int* __restrict__ cursor,
                                                      int2* __restrict__ srcW, int E,
                                                      const float* __restrict__ dinv,
                                                      const float* __restrict__ X,
                                                      const float* __restrict__ W,
                                                      __hip_bfloat16* __restrict__ Y,
                                                      int nrows) {
    int tid = threadIdx.x;
    int q = blockIdx.x / 3, k3 = blockIdx.x % 3;
    if (k3 < 2) {
        int e = (2 * q + k3) * 256 + tid;
        if (e < E) {
            int c = ei[(size_t)E + e];
            int r = ei[e];
            int pos = atomicAdd(&cursor[c], 1);
            srcW[pos] = make_int2(r, __float_as_int(dinv[r]));
        }
    } else {
        __shared__ float xsh[32][HDIM];
        int c = tid & 127;
        int g = tid >> 7;
        int r0 = q * 32;
        for (int idx = tid; idx < 32 * HDIM / 4; idx += 256) {
            int row = idx >> 5;
            int kk = (idx & 31) * 4;
            int gr = r0 + row;
            float4 v = make_float4(0.f, 0.f, 0.f, 0.f);
            if (gr < nrows) v = *(const float4*)(X + (size_t)gr * HDIM + kk);
            *(float4*)&xsh[row][kk] = v;
        }
        __syncthreads();
        float acc[16];
#pragma unroll
        for (int r = 0; r < 16; r++) acc[r] = 0.f;
        for (int k4 = 0; k4 < HDIM / 4; k4++) {
            int k = k4 * 4;
            float w0 = W[(size_t)(k + 0) * HDIM + c];
            float w1 = W[(size_t)(k + 1) * HDIM + c];
            float w2 = W[(size_t)(k + 2) * HDIM + c];
            float w3 = W[(size_t)(k + 3) * HDIM + c];
#pragma unroll
            for (int r = 0; r < 16; r++) {
                float4 xv = *(const float4*)&xsh[g * 16 + r][k];
                acc[r] = fmaf(xv.x, w0, fmaf(xv.y, w1, fmaf(xv.z, w2, fmaf(xv.w, w3, acc[r]))));
            }
        }
#pragma unroll
        for (int r = 0; r < 16; r++) {
            int gr = r0 + g * 16 + r;
            if (gr < nrows) Y[(size_t)gr * HDIM + c] = __float2bfloat16(acc[r]);
        }
    }
}

__global__ __launch_bounds__(256) void k_agg_gemm(const __hip_bfloat16* __restrict__ hin,
                                                  __hip_bfloat16* __restrict__ hout,
                                                  const int* __restrict__ ptr,
                                                  const int2* __restrict__ srcW,
                                                  const float* __restrict__ dinv,
                                                  const float* __restrict__ bias,
                                                  const float* __restrict__ W2, int n) {
    __shared__ float xsh[32][HDIM];
    int tid = threadIdx.x;
    int w = tid >> 6, lane = tid & 63;
    int fs = lane & 15, jg = lane >> 4;
    int base = blockIdx.x * 32;
    for (int i = 0; i < 8; i++) {
        int lr = w * 8 + i;
        int node = base + lr;
        if (node < n) {
            float di = dinv[node];
            float acc[8];
            agg_core(hin, ptr, srcW, node, fs, jg, di, acc);
            if (jg == 0) {
                const float4* b4 = (const float4*)(bias + fs * 8);
                float4 bb0 = b4[0], bb1 = b4[1];
                float4 v0 = make_float4(fmaf(di, acc[0], bb0.x), fmaf(di, acc[1], bb0.y),
                                        fmaf(di, acc[2], bb0.z), fmaf(di, acc[3], bb0.w));
                float4 v1 = make_float4(fmaf(di, acc[4], bb1.x), fmaf(di, acc[5], bb1.y),
                                        fmaf(di, acc[6], bb1.z), fmaf(di, acc[7], bb1.w));
                *(float4*)&xsh[lr][fs * 8]     = v0;
                *(float4*)&xsh[lr][fs * 8 + 4] = v1;
            }
        } else if (jg == 0) {
            float4 z = make_float4(0.f, 0.f, 0.f, 0.f);
            *(float4*)&xsh[lr][fs * 8]     = z;
            *(float4*)&xsh[lr][fs * 8 + 4] = z;
        }
    }
    __syncthreads();
    int c = tid & 127, g = tid >> 7;
    float acc[16];
#pragma unroll
    for (int r = 0; r < 16; r++) acc[r] = 0.f;
    for (int k4 = 0; k4 < HDIM / 4; k4++) {
        int k = k4 * 4;
        float w0 = W2[(size_t)(k + 0) * HDIM + c];
        float w1 = W2[(size_t)(k + 1) * HDIM + c];
        float w2 = W2[(size_t)(k + 2) * HDIM + c];
        float w3 = W2[(size_t)(k + 3) * HDIM + c];
#pragma unroll
        for (int r = 0; r < 16; r++) {
            float4 xv = *(const float4*)&xsh[g * 16 + r][k];
            acc[r] = fmaf(xv.x, w0, fmaf(xv.y, w1, fmaf(xv.z, w2, fmaf(xv.w, w3, acc[r]))));
        }
    }
#pragma unroll
    for (int r = 0; r < 16; r++) {
        int gr = base + g * 16 + r;
        if (gr < n) hout[(size_t)gr * HDIM + c] = __float2bfloat16(acc[r]);
    }
}

__global__ __launch_bounds__(256) void k_agg_fc(const __hip_bfloat16* __restrict__ hin,
                                                const int* __restrict__ ptr,
                                                const int2* __restrict__ srcW,
                                                const float* __restrict__ dinv,
                                                const float* __restrict__ bias,
                                                const float* __restrict__ Wfc,
                                                const float* __restrict__ bfc,
                                                float* __restrict__ out, int n) {
    int node = blockIdx.x * 4 + (threadIdx.x >> 6);
    if (node >= n) return;
    int lane = threadIdx.x & 63;
    int fs = lane & 15, jg = lane >> 4;
    float di = dinv[node];
    float acc[8];
    agg_core(hin, ptr, srcW, node, fs, jg, di, acc);
    const float4* b4 = (const float4*)(bias + fs * 8);
    float4 bb0 = b4[0], bb1 = b4[1];
    float h[8];
    h[0] = fmaf(di, acc[0], bb0.x); h[1] = fmaf(di, acc[1], bb0.y);
    h[2] = fmaf(di, acc[2], bb0.z); h[3] = fmaf(di, acc[3], bb0.w);
    h[4] = fmaf(di, acc[4], bb1.x); h[5] = fmaf(di, acc[5], bb1.y);
    h[6] = fmaf(di, acc[6], bb1.z); h[7] = fmaf(di, acc[7], bb1.w);
    int c0 = jg * 2;
    float p0 = 0.f, p1 = 0.f;
#pragma unroll
    for (int k = 0; k < 8; k++) {
        const float* wr = Wfc + (size_t)(fs * 8 + k) * CDIM + c0;
        p0 = fmaf(h[k], wr[0], p0);
        p1 = fmaf(h[k], wr[1], p1);
    }
#pragma unroll
    for (int off = 1; off < 16; off <<= 1) {
        p0 += __shfl_xor(p0, off, 64);
        p1 += __shfl_xor(p1, off, 64);
    }
    if (fs == 0) {
        out[(size_t)node * CDIM + c0]     = p0 + bfc[c0];
        out[(size_t)node * CDIM + c0 + 1] = p1 + bfc[c0 + 1];
    }
}

extern "C" void kernel_launch(void* const* d_in, const int* in_sizes, int n_in,
                              void* d_out, int out_size, void* d_ws, size_t ws_size,
                              hipStream_t stream) {
    const float* x   = (const float*)d_in[0];
    const int*   ei  = (const int*)d_in[1];
    const float* W1  = (const float*)d_in[2];
    const float* b1  = (const float*)d_in[3];
    const float* W2  = (const float*)d_in[4];
    const float* b2  = (const float*)d_in[5];
    const float* Wfc = (const float*)d_in[6];
    const float* bfc = (const float*)d_in[7];
    float* out = (float*)d_out;

    int N = in_sizes[0] / HDIM;   // 50000
    int E = in_sizes[1] / 2;      // 800000
    int Gg = (N + 31) / 32;       // 1563

    // workspace layout
    __hip_bfloat16* bufH  = (__hip_bfloat16*)d_ws;                       // N*128 bf16
    __hip_bfloat16* bufH2 = bufH + (size_t)N * HDIM;                     // N*128 bf16
    float* dinv   = (float*)(bufH2 + (size_t)N * HDIM);  // N
    int*   cnt    = (int*)(dinv + N);                    // N
    int*   status = cnt + N;                             // 16  (fallback scan)
    int*   ptr    = status + 16;                         // N+1
    int*   cursor = ptr + (N + 1);                       // N
    int*   bsum   = cursor + N;                          // 2048
    int2*  srcW   = (int2*)(((uintptr_t)(bsum + 2048) + 15) & ~(uintptr_t)15);  // E int2

    // ---- primary: single cooperative launch ----
    int occ = 0;
    hipError_t oe = hipOccupancyMaxActiveBlocksPerMultiprocessor(
        &occ, reinterpret_cast<const void*>(k_mega), 256, 0);
    bool coop = (oe == hipSuccess && occ >= 1);
    if (coop) {
        int bpc = occ > 8 ? 8 : occ;
        int grid = bpc * 256;   // 256 CUs on MI355X
        void* args[] = {(void*)&x,    (void*)&ei,   (void*)&W1,   (void*)&b1,
                        (void*)&W2,   (void*)&b2,   (void*)&Wfc,  (void*)&bfc,
                        (void*)&out,  (void*)&bufH, (void*)&bufH2,(void*)&dinv,
                        (void*)&cnt,  (void*)&ptr,  (void*)&cursor,(void*)&srcW,
                        (void*)&bsum, (void*)&N,    (void*)&E,    (void*)&Gg};
        hipError_t le = hipLaunchCooperativeKernel(
            reinterpret_cast<const void*>(k_mega), dim3(grid), dim3(256),
            args, 0, stream);
        coop = (le == hipSuccess);
    }
    if (!coop) {
        // ---- fallback: proven R11 6-launch path ----
        const int B = (N + SCAN_CHUNK - 1) / SCAN_CHUNK;
        hipMemsetAsync(cnt, 0, (size_t)(N + 16) * sizeof(int), stream);
        k_hist<<<(E + 255) / 256, 256, 0, stream>>>(ei + E, cnt, E);
        k_scan<<<B, 256, 0, stream>>>(cnt, status, ptr, cursor, dinv, N, E);
        k_scatter_gemm<<<3 * Gg, 256, 0, stream>>>(ei, cursor, srcW, E, dinv, x, W1, bufH, N);
        k_agg_gemm<<<Gg, 256, 0, stream>>>(bufH, bufH2, ptr, srcW, dinv, b1, W2, N);
        k_agg_fc<<<(N + 3) / 4, 256, 0, stream>>>(bufH2, ptr, srcW, dinv, b2, Wfc, bfc, out, N);
    }
}

// Round 15
// 328.510 us; speedup vs baseline: 2.9618x; 2.2214x over previous
//
#include <hip/hip_runtime.h>
#include <hip/hip_bf16.h>

#define HDIM 128
#define CDIM 8
#define SCAN_CHUNK 4096

// Harness contract (pinned, R1-3): float32 -> const float*, edge_index -> const int*,
// output -> float*.
// R14 post-mortem: tile-16 k_agg_gemm crashed (audit found no fault; possibly
// flaky). R15: R11-proven kernels everywhere; k_agg_gemm reworked as tile-32 /
// 512 threads: 8 waves x 4 serial nodes, 16KB LDS, ~56 VGPR -> 4 blocks/CU =
// 32 waves/CU (100% occ; R11 ran this phase at 31%). Different code path than
// the crashed tile-16 variant.
// Cross-round: random 64B-line traffic plateaus ~1.0-1.15 TB/s in both scatter
// and agg -- suspected line-rate ceiling; this round tests wave-count vs ceiling.

// ---------- histogram ----------
__global__ void k_hist(const int* __restrict__ col, int* __restrict__ cnt, int E) {
    int e = blockIdx.x * blockDim.x + threadIdx.x;
    if (e < E) atomicAdd(&cnt[col[e]], 1);
}

// ---------- single-launch decoupled-lookback scan (13 co-resident blocks) ----------
__global__ __launch_bounds__(256) void k_scan(const int* __restrict__ cnt,
                                              int* __restrict__ status,
                                              int* __restrict__ ptr,
                                              int* __restrict__ cursor,
                                              float* __restrict__ dinv,
                                              int n, int Etot) {
    int b = blockIdx.x, tid = threadIdx.x;
    int base = b * SCAN_CHUNK + tid * 16;
    int v[16];
    int s = 0;
#pragma unroll
    for (int j = 0; j < 16; j++) {
        int i = base + j;
        v[j] = (i < n) ? cnt[i] : 0;
        s += v[j];
    }
    int lane = tid & 63, wid = tid >> 6;
    int x = s;
    for (int off = 1; off < 64; off <<= 1) {
        int y = __shfl_up(x, off, 64);
        if (lane >= off) x += y;
    }
    __shared__ int wtot[4];
    __shared__ int sprefix;
    if (lane == 63) wtot[wid] = x;
    __syncthreads();
    if (tid == 0) {
        int tot = wtot[0] + wtot[1] + wtot[2] + wtot[3];
        atomicExch(&status[b], tot + 1);            // publish first (no peer deadlock)
        int pre = 0;
        for (int p = 0; p < b; p++) {
            int vv;
            do { vv = atomicAdd(&status[p], 0); } while (vv == 0);
            pre += vv - 1;
        }
        sprefix = pre;
        if (b == 0) ptr[n] = Etot;
    }
    __syncthreads();
    int woff = 0;
    for (int w = 0; w < wid; w++) woff += wtot[w];
    int excl = sprefix + woff + (x - s);
#pragma unroll
    for (int j = 0; j < 16; j++) {
        int i = base + j;
        if (i < n) {
            ptr[i] = excl;
            cursor[i] = excl;
            dinv[i] = rsqrtf((float)v[j] + 1.0f);   // +1 self-loop
        }
        excl += v[j];
    }
}

// ---------- fused scatter | gemm1, stripe-interleaved for co-residency ----------
__global__ __launch_bounds__(256) void k_scatter_gemm(const int* __restrict__ ei,
                                                      int* __restrict__ cursor,
                                                      int2* __restrict__ srcW, int E,
                                                      const float* __restrict__ dinv,
                                                      const float* __restrict__ X,
                                                      const float* __restrict__ W,
                                                      __hip_bfloat16* __restrict__ Y,
                                                      int nrows) {
    int tid = threadIdx.x;
    int q = blockIdx.x / 3, k3 = blockIdx.x % 3;
    if (k3 < 2) {
        int e = (2 * q + k3) * 256 + tid;
        if (e < E) {
            int c = ei[(size_t)E + e];
            int r = ei[e];
            int pos = atomicAdd(&cursor[c], 1);
            srcW[pos] = make_int2(r, __float_as_int(dinv[r]));
        }
    } else {
        __shared__ float xsh[32][HDIM];
        int c = tid & 127;
        int g = tid >> 7;
        int r0 = q * 32;
        for (int idx = tid; idx < 32 * HDIM / 4; idx += 256) {
            int row = idx >> 5;
            int kk = (idx & 31) * 4;
            int gr = r0 + row;
            float4 v = make_float4(0.f, 0.f, 0.f, 0.f);
            if (gr < nrows) v = *(const float4*)(X + (size_t)gr * HDIM + kk);
            *(float4*)&xsh[row][kk] = v;
        }
        __syncthreads();
        float acc[16];
#pragma unroll
        for (int r = 0; r < 16; r++) acc[r] = 0.f;
        for (int k4 = 0; k4 < HDIM / 4; k4++) {
            int k = k4 * 4;
            float w0 = W[(size_t)(k + 0) * HDIM + c];
            float w1 = W[(size_t)(k + 1) * HDIM + c];
            float w2 = W[(size_t)(k + 2) * HDIM + c];
            float w3 = W[(size_t)(k + 3) * HDIM + c];
#pragma unroll
            for (int r = 0; r < 16; r++) {
                float4 xv = *(const float4*)&xsh[g * 16 + r][k];
                acc[r] = fmaf(xv.x, w0, fmaf(xv.y, w1, fmaf(xv.z, w2, fmaf(xv.w, w3, acc[r]))));
            }
        }
#pragma unroll
        for (int r = 0; r < 16; r++) {
            int gr = r0 + g * 16 + r;
            if (gr < nrows) Y[(size_t)gr * HDIM + c] = __float2bfloat16(acc[r]);
        }
    }
}

// ---------- wave-per-node agg core: 16 fs x 4 jg, depth-2 pipeline ----------
__device__ __forceinline__ void bf8_fma(uint4 qv, float w, float* acc) {
    unsigned u[4] = {qv.x, qv.y, qv.z, qv.w};
#pragma unroll
    for (int i = 0; i < 4; i++) {
        float lo = __uint_as_float(u[i] << 16);
        float hi = __uint_as_float(u[i] & 0xFFFF0000u);
        acc[2 * i]     = fmaf(w, lo, acc[2 * i]);
        acc[2 * i + 1] = fmaf(w, hi, acc[2 * i + 1]);
    }
}

__device__ __forceinline__ void agg_core(const __hip_bfloat16* __restrict__ hin,
                                         const int* __restrict__ ptr,
                                         const int2* __restrict__ srcW,
                                         int node, int fs, int jg, float di,
                                         float acc[8]) {
#pragma unroll
    for (int k = 0; k < 8; k++) acc[k] = 0.f;
    if (jg == 0) {
        uint4 qv = ((const uint4*)(hin + (size_t)node * HDIM))[fs];
        bf8_fma(qv, di, acc);
    }
    int s = ptr[node], e = ptr[node + 1];
    int j0 = s + jg, j1 = s + jg + 4;
    int2 Z = make_int2(node, 0);
    int2 p0 = (j0 < e) ? srcW[j0] : Z;
    int2 p1 = (j1 < e) ? srcW[j1] : Z;
    int iters = (e - s + 7) >> 3;
    for (int t = 0; t < iters; t++) {
        int2 c0 = p0, c1 = p1;
        j0 += 8; j1 += 8;
        if (t + 1 < iters) {
            p0 = (j0 < e) ? srcW[j0] : Z;
            p1 = (j1 < e) ? srcW[j1] : Z;
        }
        uint4 q0 = ((const uint4*)(hin + (size_t)c0.x * HDIM))[fs];
        uint4 q1 = ((const uint4*)(hin + (size_t)c1.x * HDIM))[fs];
        bf8_fma(q0, __int_as_float(c0.y), acc);
        bf8_fma(q1, __int_as_float(c1.y), acc);
    }
#pragma unroll
    for (int k = 0; k < 8; k++) {
        acc[k] += __shfl_xor(acc[k], 16, 64);
        acc[k] += __shfl_xor(acc[k], 32, 64);
    }
}

// ---------- fused agg layer-1 + GEMM layer-2: tile 32, 512 threads ----------
// 8 waves x 4 serial nodes; 16KB LDS; ~56 VGPR -> 4 blocks/CU = 32 waves/CU
// (100% occ vs R11's 31% at 256 threads / 8 nodes per wave).
__global__ __launch_bounds__(512) void k_agg_gemm(const __hip_bfloat16* __restrict__ hin,
                                                  __hip_bfloat16* __restrict__ hout,
                                                  const int* __restrict__ ptr,
                                                  const int2* __restrict__ srcW,
                                                  const float* __restrict__ dinv,
                                                  const float* __restrict__ bias,
                                                  const float* __restrict__ W2, int n) {
    __shared__ float xsh[32][HDIM];   // 16 KB
    int tid = threadIdx.x;
    int w = tid >> 6, lane = tid & 63;        // w in 0..7
    int fs = lane & 15, jg = lane >> 4;
    int base = blockIdx.x * 32;
    for (int i = 0; i < 4; i++) {
        int lr = w * 4 + i;                   // 0..31
        int node = base + lr;
        if (node < n) {
            float di = dinv[node];
            float acc[8];
            agg_core(hin, ptr, srcW, node, fs, jg, di, acc);
            if (jg == 0) {
                const float4* b4 = (const float4*)(bias + fs * 8);
                float4 bb0 = b4[0], bb1 = b4[1];
                float4 v0 = make_float4(fmaf(di, acc[0], bb0.x), fmaf(di, acc[1], bb0.y),
                                        fmaf(di, acc[2], bb0.z), fmaf(di, acc[3], bb0.w));
                float4 v1 = make_float4(fmaf(di, acc[4], bb1.x), fmaf(di, acc[5], bb1.y),
                                        fmaf(di, acc[6], bb1.z), fmaf(di, acc[7], bb1.w));
                *(float4*)&xsh[lr][fs * 8]     = v0;
                *(float4*)&xsh[lr][fs * 8 + 4] = v1;
            }
        } else if (jg == 0) {
            float4 z = make_float4(0.f, 0.f, 0.f, 0.f);
            *(float4*)&xsh[lr][fs * 8]     = z;
            *(float4*)&xsh[lr][fs * 8 + 4] = z;
        }
    }
    __syncthreads();
    // gemm: 32 rows x 128 cols; thread (c, g) handles rows g*8..g*8+7
    int c = tid & 127, g = tid >> 7;          // g in 0..3
    float acc[8];
#pragma unroll
    for (int r = 0; r < 8; r++) acc[r] = 0.f;
    for (int k4 = 0; k4 < HDIM / 4; k4++) {
        int k = k4 * 4;
        float w0 = W2[(size_t)(k + 0) * HDIM + c];
        float w1 = W2[(size_t)(k + 1) * HDIM + c];
        float w2 = W2[(size_t)(k + 2) * HDIM + c];
        float w3 = W2[(size_t)(k + 3) * HDIM + c];
#pragma unroll
        for (int r = 0; r < 8; r++) {
            float4 xv = *(const float4*)&xsh[g * 8 + r][k];
            acc[r] = fmaf(xv.x, w0, fmaf(xv.y, w1, fmaf(xv.z, w2, fmaf(xv.w, w3, acc[r]))));
        }
    }
#pragma unroll
    for (int r = 0; r < 8; r++) {
        int gr = base + g * 8 + r;
        if (gr < n) hout[(size_t)gr * HDIM + c] = __float2bfloat16(acc[r]);
    }
}

// ---------- agg layer 2 + fused FC ----------
__global__ __launch_bounds__(256) void k_agg_fc(const __hip_bfloat16* __restrict__ hin,
                                                const int* __restrict__ ptr,
                                                const int2* __restrict__ srcW,
                                                const float* __restrict__ dinv,
                                                const float* __restrict__ bias,
                                                const float* __restrict__ Wfc,
                                                const float* __restrict__ bfc,
                                                float* __restrict__ out, int n) {
    int node = blockIdx.x * 4 + (threadIdx.x >> 6);
    if (node >= n) return;
    int lane = threadIdx.x & 63;
    int fs = lane & 15, jg = lane >> 4;
    float di = dinv[node];
    float acc[8];
    agg_core(hin, ptr, srcW, node, fs, jg, di, acc);
    const float4* b4 = (const float4*)(bias + fs * 8);
    float4 bb0 = b4[0], bb1 = b4[1];
    float h[8];
    h[0] = fmaf(di, acc[0], bb0.x); h[1] = fmaf(di, acc[1], bb0.y);
    h[2] = fmaf(di, acc[2], bb0.z); h[3] = fmaf(di, acc[3], bb0.w);
    h[4] = fmaf(di, acc[4], bb1.x); h[5] = fmaf(di, acc[5], bb1.y);
    h[6] = fmaf(di, acc[6], bb1.z); h[7] = fmaf(di, acc[7], bb1.w);
    int c0 = jg * 2;
    float p0 = 0.f, p1 = 0.f;
#pragma unroll
    for (int k = 0; k < 8; k++) {
        const float* wr = Wfc + (size_t)(fs * 8 + k) * CDIM + c0;
        p0 = fmaf(h[k], wr[0], p0);
        p1 = fmaf(h[k], wr[1], p1);
    }
#pragma unroll
    for (int off = 1; off < 16; off <<= 1) {
        p0 += __shfl_xor(p0, off, 64);
        p1 += __shfl_xor(p1, off, 64);
    }
    if (fs == 0) {
        out[(size_t)node * CDIM + c0]     = p0 + bfc[c0];
        out[(size_t)node * CDIM + c0 + 1] = p1 + bfc[c0 + 1];
    }
}

extern "C" void kernel_launch(void* const* d_in, const int* in_sizes, int n_in,
                              void* d_out, int out_size, void* d_ws, size_t ws_size,
                              hipStream_t stream) {
    const float* x   = (const float*)d_in[0];
    const int*   ei  = (const int*)d_in[1];
    const float* W1  = (const float*)d_in[2];
    const float* b1  = (const float*)d_in[3];
    const float* W2  = (const float*)d_in[4];
    const float* b2  = (const float*)d_in[5];
    const float* Wfc = (const float*)d_in[6];
    const float* bfc = (const float*)d_in[7];
    float* out = (float*)d_out;

    const int N = in_sizes[0] / HDIM;   // 50000
    const int E = in_sizes[1] / 2;      // 800000
    const int B = (N + SCAN_CHUNK - 1) / SCAN_CHUNK;   // 13

    // workspace layout
    __hip_bfloat16* bufH  = (__hip_bfloat16*)d_ws;                       // N*128 bf16
    __hip_bfloat16* bufH2 = bufH + (size_t)N * HDIM;                     // N*128 bf16
    float* dinv   = (float*)(bufH2 + (size_t)N * HDIM);  // N
    int*   cnt    = (int*)(dinv + N);                    // N      } zeroed together
    int*   status = cnt + N;                             // 16     }
    int*   ptr    = status + 16;                         // N+1
    int*   cursor = ptr + (N + 1);                       // N
    int2*  srcW   = (int2*)(((uintptr_t)(cursor + N) + 15) & ~(uintptr_t)15);  // E int2

    hipMemsetAsync(cnt, 0, (size_t)(N + 16) * sizeof(int), stream);
    k_hist<<<(E + 255) / 256, 256, 0, stream>>>(ei + E, cnt, E);
    k_scan<<<B, 256, 0, stream>>>(cnt, status, ptr, cursor, dinv, N, E);

    const int Gg = (N + 31) / 32;          // 1563; 2*Gg=3126 >= 3125 scatter units
    k_scatter_gemm<<<3 * Gg, 256, 0, stream>>>(ei, cursor, srcW, E, dinv, x, W1, bufH, N);

    k_agg_gemm<<<Gg, 512, 0, stream>>>(bufH, bufH2, ptr, srcW, dinv, b1, W2, N);
    k_agg_fc<<<(N + 3) / 4, 256, 0, stream>>>(bufH2, ptr, srcW, dinv, b2, Wfc, bfc, out, N);
}